// Round 2
// 397.443 us; speedup vs baseline: 1.0090x; 1.0090x over previous
//
#include <hip/hip_runtime.h>

#define NB 8
#define NN 2048
#define NF 256

typedef __attribute__((ext_vector_type(8))) short bf16x8;
typedef __attribute__((ext_vector_type(4))) float f32x4;

__device__ __forceinline__ unsigned short f2bf(float x) {
  union { float f; unsigned int i; } c; c.f = x;
  unsigned int r = c.i + 0x7FFFu + ((c.i >> 16) & 1u);
  return (unsigned short)(r >> 16);
}
// round-half-up bf16 (1 add + 1 shift) — hot convert paths
__device__ __forceinline__ unsigned short f2bf_fast(float x) {
  union { float f; unsigned int i; } c; c.f = x;
  return (unsigned short)((c.i + 0x8000u) >> 16);
}
__device__ __forceinline__ bf16x8 cvt8(float4 c0, float4 c1) {
  union { bf16x8 v8; unsigned short us[8]; } cu;
  cu.us[0] = f2bf_fast(c0.x); cu.us[1] = f2bf_fast(c0.y);
  cu.us[2] = f2bf_fast(c0.z); cu.us[3] = f2bf_fast(c0.w);
  cu.us[4] = f2bf_fast(c1.x); cu.us[5] = f2bf_fast(c1.y);
  cu.us[6] = f2bf_fast(c1.z); cu.us[7] = f2bf_fast(c1.w);
  return cu.v8;
}

// ---------------------------------------------------------------------------
// k_prep: WT[f][k] = bf16(W[k][f]);  u = W @ a1, v = W @ a2  (fp32)
// ---------------------------------------------------------------------------
__global__ __launch_bounds__(256) void k_prep(
    const float* __restrict__ W, const float* __restrict__ a,
    unsigned short* __restrict__ WT, float* __restrict__ u, float* __restrict__ v) {
  int t = threadIdx.x;
  if (blockIdx.x < 256) {
    int k = blockIdx.x;
    WT[t * 256 + k] = f2bf(W[k * 256 + t]);
  } else {
    float su = 0.f, sv = 0.f;
    for (int o = 0; o < 256; ++o) {
      float w = W[t * 256 + o];
      su += w * a[o];
      sv += w * a[256 + o];
    }
    u[t] = su; v[t] = sv;
  }
}

// ---------------------------------------------------------------------------
// k_wht: WhT[b][f][i] = sum_k W[k][f] * h[b][i][k]
// grid 512: b(8) x [fblk(4,64f) x iblk(16,128i)]; 4 waves (2f x 2i), wave 32f x 64i
// ---------------------------------------------------------------------------
__global__ __launch_bounds__(256) void k_wht(
    const float* __restrict__ h, const unsigned short* __restrict__ WTr,
    unsigned short* __restrict__ WhT) {
  int bx = blockIdx.x;
  int b = bx >> 6;
  int t = bx & 63;
  int fBlk = (t >> 4) * 64;
  int iBlk = (t & 15) * 128;
  int wave = threadIdx.x >> 6, lane = threadIdx.x & 63;
  int fW = fBlk + (wave >> 1) * 32;
  int iW = iBlk + (wave & 1) * 64;
  int l15 = lane & 15, q8 = (lane >> 4) * 8;
  const float* hB = h + (size_t)b * NN * NF;

  f32x4 acc[2][4];
#pragma unroll
  for (int mt = 0; mt < 2; ++mt)
#pragma unroll
    for (int nt = 0; nt < 4; ++nt)
      acc[mt][nt] = (f32x4){0.f, 0.f, 0.f, 0.f};

  for (int k0 = 0; k0 < NF; k0 += 32) {
    int kk = k0 + q8;
    bf16x8 af[2], bfr[4];
#pragma unroll
    for (int mt = 0; mt < 2; ++mt) {
      int f = fW + mt * 16 + l15;
      af[mt] = *(const bf16x8*)(WTr + f * 256 + kk);
    }
#pragma unroll
    for (int nt = 0; nt < 4; ++nt) {
      int i = iW + nt * 16 + l15;
      const float* p = hB + (size_t)i * NF + kk;
      bfr[nt] = cvt8(*(const float4*)p, *(const float4*)(p + 4));
    }
#pragma unroll
    for (int mt = 0; mt < 2; ++mt)
#pragma unroll
      for (int nt = 0; nt < 4; ++nt)
        acc[mt][nt] = __builtin_amdgcn_mfma_f32_16x16x32_bf16(af[mt], bfr[nt], acc[mt][nt], 0, 0, 0);
  }

  unsigned short* WhTb = WhT + (size_t)b * NF * NN;
  int q4 = (lane >> 4) * 4;
#pragma unroll
  for (int mt = 0; mt < 2; ++mt)
#pragma unroll
    for (int nt = 0; nt < 4; ++nt)
#pragma unroll
      for (int r = 0; r < 4; ++r) {
        int f = fW + mt * 16 + q4 + r;
        int i = iW + nt * 16 + l15;
        WhTb[(size_t)f * NN + i] = f2bf(acc[mt][nt][r]);
      }
}

// ---------------------------------------------------------------------------
// k_proj: Wh1[row] = h[row,:] . u ; Wh2[row] = h[row,:] . v  (wave per row, fp32)
// ---------------------------------------------------------------------------
__global__ __launch_bounds__(256) void k_proj(
    const float* __restrict__ h, const float* __restrict__ u,
    const float* __restrict__ v, float* __restrict__ Wh1, float* __restrict__ Wh2) {
  int row = blockIdx.x * 4 + (threadIdx.x >> 6);
  int lane = threadIdx.x & 63;
  float4 hv = *(const float4*)(h + (size_t)row * NF + lane * 4);
  const float* up = u + lane * 4;
  const float* vp = v + lane * 4;
  float su = hv.x * up[0] + hv.y * up[1] + hv.z * up[2] + hv.w * up[3];
  float sv = hv.x * vp[0] + hv.y * vp[1] + hv.z * vp[2] + hv.w * vp[3];
#pragma unroll
  for (int off = 32; off >= 1; off >>= 1) {
    su += __shfl_xor(su, off);
    sv += __shfl_xor(sv, off);
  }
  if (lane == 0) { Wh1[row] = su; Wh2[row] = sv; }
}

// ---------------------------------------------------------------------------
// k_fuse: softmax (16 rows) + att@WhT + h+elu epilogue, one block per row-tile.
// 512 threads / 8 waves: LDS (64 KB) caps residency at 2 blocks/CU, so pack
// 8 waves per block -> 16 waves/CU (4/SIMD), 2x the old 256-thread config.
// Phase 1: each wave handles 2 rows (32 loads in flight); writes fp32 att to
//          global and normalized bf16 att into XOR-swizzled LDS (swz = row*8).
// Phase 2: GEMM 16i x 256f x 2048j; wave owns a 32-wide f-stripe; A from LDS
//          ds_read_b128 (swizzled, conflict-free), B = WhT[b][f][j] 16B frags
//          (L2-resident); fused out = h + elu.
// grid 1024: b(8) x itile(128,16i); LDS 64 KB -> 2 blocks/CU.
// ---------------------------------------------------------------------------
__global__ __launch_bounds__(512, 4) void k_fuse(
    const int* __restrict__ adj, const float* __restrict__ Wh1,
    const float* __restrict__ Wh2, const unsigned short* __restrict__ WhT,
    const float* __restrict__ h, float* __restrict__ att, float* __restrict__ out) {
  __shared__ unsigned short satt[16 * 2048];  // 64 KB, XOR-swizzled rows
  const float NEGBIG = -9.0e15f;
  int bx = blockIdx.x;
  int b = bx >> 7;
  int i0 = (bx & 127) * 16;
  int wave = threadIdx.x >> 6, lane = threadIdx.x & 63;
  const float* w2 = Wh2 + ((size_t)b << 11);

  // ---------------- phase 1: masked-softmax for rows i0+wave*2 .. +1 -------
  float s[2][32];
  int rowbase = b * NN + i0 + wave * 2;
#pragma unroll
  for (int rr = 0; rr < 2; ++rr) {
    const int* arow = adj + (size_t)(rowbase + rr) * NN;
    float w1 = Wh1[rowbase + rr];
#pragma unroll
    for (int c = 0; c < 8; ++c) {
      int j = c * 256 + lane * 4;
      int4 av = *(const int4*)(arow + j);
      float4 pv = *(const float4*)(w2 + j);
      float x;
      x = w1 + pv.x; x = x >= 0.f ? x : 0.2f * x; s[rr][c*4+0] = (av.x > 0) ? x : NEGBIG;
      x = w1 + pv.y; x = x >= 0.f ? x : 0.2f * x; s[rr][c*4+1] = (av.y > 0) ? x : NEGBIG;
      x = w1 + pv.z; x = x >= 0.f ? x : 0.2f * x; s[rr][c*4+2] = (av.z > 0) ? x : NEGBIG;
      x = w1 + pv.w; x = x >= 0.f ? x : 0.2f * x; s[rr][c*4+3] = (av.w > 0) ? x : NEGBIG;
    }
  }

  float inv[2];
#pragma unroll
  for (int rr = 0; rr < 2; ++rr) {
    float m = s[rr][0];
#pragma unroll
    for (int k = 1; k < 32; ++k) m = fmaxf(m, s[rr][k]);
#pragma unroll
    for (int off = 32; off >= 1; off >>= 1) m = fmaxf(m, __shfl_xor(m, off));
    float sum = 0.f;
#pragma unroll
    for (int k = 0; k < 32; ++k) { s[rr][k] = __expf(s[rr][k] - m); sum += s[rr][k]; }
#pragma unroll
    for (int off = 32; off >= 1; off >>= 1) sum += __shfl_xor(sum, off);
    inv[rr] = 1.0f / sum;
  }

#pragma unroll
  for (int rr = 0; rr < 2; ++rr) {
    int row_local = wave * 2 + rr;
    int swz = row_local * 8;
    float* orow = att + (size_t)(rowbase + rr) * NN;
    unsigned short* srow = satt + row_local * 2048;
    float iv = inv[rr];
#pragma unroll
    for (int c = 0; c < 8; ++c) {
      int j = c * 256 + lane * 4;
      float a0 = s[rr][c*4+0] * iv, a1 = s[rr][c*4+1] * iv;
      float a2 = s[rr][c*4+2] * iv, a3 = s[rr][c*4+3] * iv;
      *(float4*)(orow + j) = make_float4(a0, a1, a2, a3);
      // LDS: 4 bf16 (8B) at swizzled offset; groups of 8 permuted by swz
      int e = ((j & ~7) ^ swz) + (j & 7);
      union { short4 v4; unsigned short us[4]; } pk;
      pk.us[0] = f2bf_fast(a0); pk.us[1] = f2bf_fast(a1);
      pk.us[2] = f2bf_fast(a2); pk.us[3] = f2bf_fast(a3);
      *(short4*)(srow + e) = pk.v4;
    }
  }

  __syncthreads();

  // ---------------- phase 2: h_prime = att @ Wh, out = h + elu -------------
  int fW = wave * 32;
  int l15 = lane & 15, q8 = (lane >> 4) * 8;
  const unsigned short* WTb = WhT + (size_t)b * NF * NN;
  const unsigned short* aRow = satt + l15 * 2048;
  int swzA = l15 * 8;

  f32x4 acc[2];
#pragma unroll
  for (int nt = 0; nt < 2; ++nt) acc[nt] = (f32x4){0.f, 0.f, 0.f, 0.f};

  for (int kk = 0; kk < NN; kk += 32) {
    bf16x8 afr = *(const bf16x8*)(aRow + (((kk + q8) ^ swzA)));
    bf16x8 bfr[2];
#pragma unroll
    for (int nt = 0; nt < 2; ++nt) {
      int f = fW + nt * 16 + l15;
      bfr[nt] = *(const bf16x8*)(WTb + (size_t)f * NN + kk + q8);
    }
#pragma unroll
    for (int nt = 0; nt < 2; ++nt)
      acc[nt] = __builtin_amdgcn_mfma_f32_16x16x32_bf16(afr, bfr[nt], acc[nt], 0, 0, 0);
  }

  int q4 = (lane >> 4) * 4;
#pragma unroll
  for (int nt = 0; nt < 2; ++nt)
#pragma unroll
    for (int r = 0; r < 4; ++r) {
      int i = i0 + q4 + r;
      int f = fW + nt * 16 + l15;
      size_t idx = ((size_t)(b * NN + i)) * NF + f;
      float hp = acc[nt][r];
      float el = hp > 0.f ? hp : expm1f(hp);
      out[idx] = h[idx] + el;
    }
}

// ---------------------------------------------------------------------------
extern "C" void kernel_launch(void* const* d_in, const int* in_sizes, int n_in,
                              void* d_out, int out_size, void* d_ws, size_t ws_size,
                              hipStream_t stream) {
  // identify inputs by element count (all four are distinct)
  const float* h = nullptr; const int* adj = nullptr;
  const float* W = nullptr; const float* a = nullptr;
  for (int i = 0; i < n_in; ++i) {
    int s = in_sizes[i];
    if (s == NB * NN * NF) h = (const float*)d_in[i];
    else if (s == NB * NN * NN) adj = (const int*)d_in[i];
    else if (s == NF * NF) W = (const float*)d_in[i];
    else if (s == 2 * NF) a = (const float*)d_in[i];
  }

  float* out = (float*)d_out;                              // [8,2048,256] fp32
  float* att = out + (size_t)NB * NN * NF;                 // [8,2048,2048] fp32

  // ws footprint ~8.26 MB (proven safe)
  char* ws = (char*)d_ws;
  unsigned short* WhT = (unsigned short*)ws;               // 8 MB [8][256][2048] bf16
  unsigned short* WTr = (unsigned short*)(ws + 8388608);   // 128 KB [256][256] bf16
  float* u   = (float*)(ws + 8388608 + 131072);            // 1 KB
  float* v   = u + 256;                                    // 1 KB
  float* Wh1 = v + 256;                                    // 64 KB
  float* Wh2 = Wh1 + NB * NN;                              // 64 KB

  k_prep<<<257, 256, 0, stream>>>(W, a, WTr, u, v);
  k_wht<<<512, 256, 0, stream>>>(h, WTr, WhT);
  k_proj<<<NB * NN / 4, 256, 0, stream>>>(h, u, v, Wh1, Wh2);
  k_fuse<<<NB * 128, 512, 0, stream>>>(adj, Wh1, Wh2, WhT, h, att, out);
}